// Round 3
// baseline (454.326 us; speedup 1.0000x reference)
//
#include <hip/hip_runtime.h>

#define DIM 64

// ---------------- int degree histogram ----------------
__global__ void hist_kernel(const int* __restrict__ dst, int* __restrict__ deg, int E) {
    int tid = blockIdx.x * blockDim.x + threadIdx.x;
    int stride = gridDim.x * blockDim.x;
    for (int e = tid; e < E; e += stride)
        atomicAdd(&deg[dst[e]], 1);
}

// ---------------- scan stage A: per-block sums ----------------
__global__ void scanA_kernel(const int* __restrict__ deg, int* __restrict__ blockSums, int N) {
    __shared__ int tmp[256];
    int t = threadIdx.x;
    int i = blockIdx.x * 256 + t;
    int v = (i < N) ? deg[i] : 0;
    tmp[t] = v;
    __syncthreads();
    for (int off = 128; off > 0; off >>= 1) {
        if (t < off) tmp[t] += tmp[t + off];
        __syncthreads();
    }
    if (t == 0) blockSums[blockIdx.x] = tmp[0];
}

// ---------------- scan stage B: exclusive scan of block sums (1 block) ----------------
__global__ void scanB_kernel(int* __restrict__ blockSums, int nblocks) {
    __shared__ int tmp[256];
    __shared__ int carry;
    int t = threadIdx.x;
    if (t == 0) carry = 0;
    __syncthreads();
    for (int base = 0; base < nblocks; base += 256) {
        int idx = base + t;
        int v = (idx < nblocks) ? blockSums[idx] : 0;
        tmp[t] = v;
        __syncthreads();
        for (int off = 1; off < 256; off <<= 1) {
            int add = (t >= off) ? tmp[t - off] : 0;
            __syncthreads();
            tmp[t] += add;
            __syncthreads();
        }
        int incl = tmp[t];
        int excl = incl - v + carry;
        if (idx < nblocks) blockSums[idx] = excl;
        int chunkTotal = tmp[255];
        __syncthreads();
        if (t == 0) carry += chunkTotal;
        __syncthreads();
    }
}

// ---------------- scan stage C: per-element exclusive offsets ----------------
__global__ void scanC_kernel(const int* __restrict__ deg, const int* __restrict__ blockOff,
                             int* __restrict__ row_start, int* __restrict__ cursor, int N) {
    __shared__ int tmp[256];
    int b = blockIdx.x, t = threadIdx.x;
    int i = b * 256 + t;
    int v = (i < N) ? deg[i] : 0;
    tmp[t] = v;
    __syncthreads();
    for (int off = 1; off < 256; off <<= 1) {
        int add = (t >= off) ? tmp[t - off] : 0;
        __syncthreads();
        tmp[t] += add;
        __syncthreads();
    }
    int excl = tmp[t] - v + blockOff[b];
    if (i < N) {
        row_start[i] = excl;
        cursor[i] = excl;
        if (i == N - 1) row_start[N] = excl + v;
    }
}

// ---------------- bucket fill: csr_src grouped by dst ----------------
__global__ void bucket_kernel(const int* __restrict__ src, const int* __restrict__ dst,
                              int* __restrict__ cursor, int* __restrict__ csr_src, int E) {
    int tid = blockIdx.x * blockDim.x + threadIdx.x;
    int stride = gridDim.x * blockDim.x;
    for (int e = tid; e < E; e += stride) {
        int p = atomicAdd(&cursor[dst[e]], 1);
        csr_src[p] = src[e];
    }
}

// ---------------- hp = relu(h @ Wp^T + bp) ----------------
__global__ void proj_kernel(const float* __restrict__ h,
                            const float* __restrict__ Wp,
                            const float* __restrict__ bp,
                            float* __restrict__ hp, int n)
{
    __shared__ float WpT[DIM][DIM + 1];
    __shared__ float bsh[DIM];
    int tid = threadIdx.x;
    for (int i = tid; i < DIM * DIM; i += 256) {
        int d = i / DIM, k = i % DIM;
        WpT[k][d] = Wp[i];
    }
    if (tid < DIM) bsh[tid] = bp[tid];
    __syncthreads();
    int wave = tid >> 6, lane = tid & 63;
    for (int base = blockIdx.x * 4; base < n; base += gridDim.x * 4) {
        int r = base + wave;
        if (r >= n) continue;
        float hval = h[(size_t)r * DIM + lane];
        float acc = bsh[lane];
        #pragma unroll
        for (int k = 0; k < DIM; ++k) {
            float hb = __shfl(hval, k);
            acc += hb * WpT[k][lane];
        }
        hp[(size_t)r * DIM + lane] = fmaxf(acc, 0.0f);
    }
}

// ---------------- fused: agg (CSR gather) -> combine -> LayerNorm ----------------
// LDS exactly 32 KiB: two XOR-swizzled weight tiles (WT[k][lane^k]) -> 5 blocks/CU.
// Neighbor indices batch-loaded (one coalesced load per 64 edges) and broadcast
// via __shfl; gathers issued in chunks of 8 independent loads.
__global__ void __launch_bounds__(256, 5)
agg_combine_ln_kernel(const float* __restrict__ h,
                      const float* __restrict__ hp,
                      const int* __restrict__ row_start,
                      const int* __restrict__ csr_src,
                      const float* __restrict__ Wl,
                      const float* __restrict__ bl,
                      const float* __restrict__ Wr,
                      const float* __restrict__ gamma,
                      const float* __restrict__ beta,
                      float* __restrict__ out, int n)
{
    __shared__ float WlT[DIM * DIM];   // [k][d^k]
    __shared__ float WrT[DIM * DIM];   // [k][d^k]
    int tid = threadIdx.x;
    for (int i = tid; i < DIM * DIM; i += 256) {
        int d = i >> 6, k = i & 63;        // reads Wl[d*64+k] coalesced
        WlT[(k << 6) | (d ^ k)] = Wl[i];
        WrT[(k << 6) | (d ^ k)] = Wr[i];
    }
    __syncthreads();
    int wave = tid >> 6, lane = tid & 63;
    float bl_r = bl[lane];
    float g_r  = gamma[lane];
    float be_r = beta[lane];

    for (int base = blockIdx.x * 4; base < n; base += gridDim.x * 4) {
        int r = base + wave;
        if (r >= n) continue;
        int rs = row_start[r];
        int re = row_start[r + 1];
        int deg = re - rs;

        float acc = 0.0f;
        for (int jb = 0; jb < deg; jb += 64) {
            int nb = deg - jb; if (nb > 64) nb = 64;
            // one coalesced load: lane holds index of edge jb+lane
            int idxv = (jb + lane < deg) ? csr_src[rs + jb + lane] : 0;
            int c = 0;
            for (; c + 8 <= nb; c += 8) {
                int s0 = __shfl(idxv, c + 0);
                int s1 = __shfl(idxv, c + 1);
                int s2 = __shfl(idxv, c + 2);
                int s3 = __shfl(idxv, c + 3);
                int s4 = __shfl(idxv, c + 4);
                int s5 = __shfl(idxv, c + 5);
                int s6 = __shfl(idxv, c + 6);
                int s7 = __shfl(idxv, c + 7);
                float v0 = hp[(size_t)s0 * DIM + lane];
                float v1 = hp[(size_t)s1 * DIM + lane];
                float v2 = hp[(size_t)s2 * DIM + lane];
                float v3 = hp[(size_t)s3 * DIM + lane];
                float v4 = hp[(size_t)s4 * DIM + lane];
                float v5 = hp[(size_t)s5 * DIM + lane];
                float v6 = hp[(size_t)s6 * DIM + lane];
                float v7 = hp[(size_t)s7 * DIM + lane];
                acc += v0; acc += v1; acc += v2; acc += v3;
                acc += v4; acc += v5; acc += v6; acc += v7;
            }
            for (; c < nb; ++c) {
                int s = __shfl(idxv, c);
                acc += hp[(size_t)s * DIM + lane];
            }
        }
        float dg = (float)(deg > 1 ? deg : 1);
        float av = acc / dg;
        float hv = h[(size_t)r * DIM + lane];

        float o = bl_r;
        #pragma unroll
        for (int k = 0; k < DIM; ++k) {
            float ab = __shfl(av, k);
            float hb = __shfl(hv, k);
            o += ab * WlT[(k << 6) | (lane ^ k)] + hb * WrT[(k << 6) | (lane ^ k)];
        }
        // LayerNorm across 64 lanes (biased variance, eps=1e-5)
        float mu = o;
        #pragma unroll
        for (int off = 32; off > 0; off >>= 1) mu += __shfl_xor(mu, off);
        mu *= (1.0f / 64.0f);
        float d0 = o - mu;
        float var = d0 * d0;
        #pragma unroll
        for (int off = 32; off > 0; off >>= 1) var += __shfl_xor(var, off);
        var *= (1.0f / 64.0f);
        float inv = rsqrtf(var + 1e-5f);
        out[(size_t)r * DIM + lane] = d0 * inv * g_r + be_r;
    }
}

extern "C" void kernel_launch(void* const* d_in, const int* in_sizes, int n_in,
                              void* d_out, int out_size, void* d_ws, size_t ws_size,
                              hipStream_t stream)
{
    const float* x      = (const float*)d_in[0];
    const int*   ei     = (const int*)d_in[1];
    const float* W_proj = (const float*)d_in[2];
    const float* b_proj = (const float*)d_in[3];
    const float* W_l    = (const float*)d_in[4];
    const float* b_l    = (const float*)d_in[5];
    const float* W_r    = (const float*)d_in[6];
    const float* gamma  = (const float*)d_in[7];
    const float* beta   = (const float*)d_in[8];

    const int N = in_sizes[0] / DIM;
    const int E = in_sizes[1] / 2;
    const int L = in_sizes[2] / (DIM * DIM);

    const int* src  = ei;
    const int* dstp = ei + E;

    const int nblocks = (N + 255) / 256;

    float* hp        = (float*)d_ws;
    float* h1        = hp + (size_t)N * DIM;
    int*   degi      = (int*)(h1 + (size_t)N * DIM);
    int*   row_start = degi + N;
    int*   cursor    = row_start + N + 1;
    int*   csr_src   = cursor + N;
    int*   blockSums = csr_src + E;

    // ---- build CSR (once; shared by both layers) ----
    hipMemsetAsync(degi, 0, (size_t)N * sizeof(int), stream);
    hist_kernel<<<2048, 256, 0, stream>>>(dstp, degi, E);
    scanA_kernel<<<nblocks, 256, 0, stream>>>(degi, blockSums, N);
    scanB_kernel<<<1, 256, 0, stream>>>(blockSums, nblocks);
    scanC_kernel<<<nblocks, 256, 0, stream>>>(degi, blockSums, row_start, cursor, N);
    bucket_kernel<<<2048, 256, 0, stream>>>(src, dstp, cursor, csr_src, E);

    // ---- layers ----
    const float* hin = x;
    for (int l = 0; l < L; ++l) {
        proj_kernel<<<2048, 256, 0, stream>>>(hin, W_proj + (size_t)l * DIM * DIM,
                                              b_proj + (size_t)l * DIM, hp, N);
        float* outp = (l == L - 1) ? (float*)d_out : h1;
        agg_combine_ln_kernel<<<2048, 256, 0, stream>>>(hin, hp, row_start, csr_src,
                                                        W_l + (size_t)l * DIM * DIM, b_l + (size_t)l * DIM,
                                                        W_r + (size_t)l * DIM * DIM,
                                                        gamma + (size_t)l * DIM, beta + (size_t)l * DIM,
                                                        outp, N);
        hin = h1;
    }
}

// Round 4
// 440.141 us; speedup vs baseline: 1.0322x; 1.0322x over previous
//
#include <hip/hip_runtime.h>

#define DIM 64

// ---------------- int degree histogram ----------------
__global__ void hist_kernel(const int* __restrict__ dst, int* __restrict__ deg, int E) {
    int tid = blockIdx.x * blockDim.x + threadIdx.x;
    int stride = gridDim.x * blockDim.x;
    for (int e = tid; e < E; e += stride)
        atomicAdd(&deg[dst[e]], 1);
}

// ---------------- scan stage A: per-block sums ----------------
__global__ void scanA_kernel(const int* __restrict__ deg, int* __restrict__ blockSums, int N) {
    __shared__ int tmp[256];
    int t = threadIdx.x;
    int i = blockIdx.x * 256 + t;
    int v = (i < N) ? deg[i] : 0;
    tmp[t] = v;
    __syncthreads();
    for (int off = 128; off > 0; off >>= 1) {
        if (t < off) tmp[t] += tmp[t + off];
        __syncthreads();
    }
    if (t == 0) blockSums[blockIdx.x] = tmp[0];
}

// ---------------- scan stage B: exclusive scan of block sums (1 block) ----------------
__global__ void scanB_kernel(int* __restrict__ blockSums, int nblocks) {
    __shared__ int tmp[256];
    __shared__ int carry;
    int t = threadIdx.x;
    if (t == 0) carry = 0;
    __syncthreads();
    for (int base = 0; base < nblocks; base += 256) {
        int idx = base + t;
        int v = (idx < nblocks) ? blockSums[idx] : 0;
        tmp[t] = v;
        __syncthreads();
        for (int off = 1; off < 256; off <<= 1) {
            int add = (t >= off) ? tmp[t - off] : 0;
            __syncthreads();
            tmp[t] += add;
            __syncthreads();
        }
        int incl = tmp[t];
        int excl = incl - v + carry;
        if (idx < nblocks) blockSums[idx] = excl;
        int chunkTotal = tmp[255];
        __syncthreads();
        if (t == 0) carry += chunkTotal;
        __syncthreads();
    }
}

// ---------------- scan stage C: per-element exclusive offsets ----------------
__global__ void scanC_kernel(const int* __restrict__ deg, const int* __restrict__ blockOff,
                             int* __restrict__ row_start, int* __restrict__ cursor, int N) {
    __shared__ int tmp[256];
    int b = blockIdx.x, t = threadIdx.x;
    int i = b * 256 + t;
    int v = (i < N) ? deg[i] : 0;
    tmp[t] = v;
    __syncthreads();
    for (int off = 1; off < 256; off <<= 1) {
        int add = (t >= off) ? tmp[t - off] : 0;
        __syncthreads();
        tmp[t] += add;
        __syncthreads();
    }
    int excl = tmp[t] - v + blockOff[b];
    if (i < N) {
        row_start[i] = excl;
        cursor[i] = excl;
        if (i == N - 1) row_start[N] = excl + v;
    }
}

// ---------------- bucket fill: csr_src grouped by dst ----------------
__global__ void bucket_kernel(const int* __restrict__ src, const int* __restrict__ dst,
                              int* __restrict__ cursor, int* __restrict__ csr_src, int E) {
    int tid = blockIdx.x * blockDim.x + threadIdx.x;
    int stride = gridDim.x * blockDim.x;
    for (int e = tid; e < E; e += stride) {
        int p = atomicAdd(&cursor[dst[e]], 1);
        csr_src[p] = src[e];
    }
}

// ---------------- hp = relu(h @ Wp^T + bp) ----------------
__global__ void proj_kernel(const float* __restrict__ h,
                            const float* __restrict__ Wp,
                            const float* __restrict__ bp,
                            float* __restrict__ hp, int n)
{
    __shared__ float WpT[DIM][DIM + 1];
    __shared__ float bsh[DIM];
    int tid = threadIdx.x;
    for (int i = tid; i < DIM * DIM; i += 256) {
        int d = i / DIM, k = i % DIM;
        WpT[k][d] = Wp[i];
    }
    if (tid < DIM) bsh[tid] = bp[tid];
    __syncthreads();
    int wave = tid >> 6, lane = tid & 63;
    for (int base = blockIdx.x * 4; base < n; base += gridDim.x * 4) {
        int r = base + wave;
        if (r >= n) continue;
        float hval = h[(size_t)r * DIM + lane];
        float acc = bsh[lane];
        #pragma unroll
        for (int k = 0; k < DIM; ++k) {
            float hb = __shfl(hval, k);
            acc += hb * WpT[k][lane];
        }
        hp[(size_t)r * DIM + lane] = fmaxf(acc, 0.0f);
    }
}

// ---------------- fused: agg (CSR gather, float4-wide) -> combine -> LayerNorm ----
// Gather: wave split into 4 groups x 16 lanes; each group loads a whole hp row
// per float4 instruction (16 lanes x 16B = 256B = 1 row). 4 independent loads
// in flight/lane => 16 rows (4KB) in flight per wave. Per-group float4 partials
// merged once per row with an 8-shuffle butterfly (xor 16,32).
__global__ void __launch_bounds__(256, 4)
agg_combine_ln_kernel(const float* __restrict__ h,
                      const float* __restrict__ hp,
                      const int* __restrict__ row_start,
                      const int* __restrict__ csr_src,
                      const float* __restrict__ Wl,
                      const float* __restrict__ bl,
                      const float* __restrict__ Wr,
                      const float* __restrict__ gamma,
                      const float* __restrict__ beta,
                      float* __restrict__ out, int n)
{
    __shared__ float WlT[DIM * DIM];   // [k][d^k]
    __shared__ float WrT[DIM * DIM];   // [k][d^k]
    int tid = threadIdx.x;
    for (int i = tid; i < DIM * DIM; i += 256) {
        int d = i >> 6, k = i & 63;
        WlT[(k << 6) | (d ^ k)] = Wl[i];
        WrT[(k << 6) | (d ^ k)] = Wr[i];
    }
    __syncthreads();
    int wave = tid >> 6, lane = tid & 63;
    int g = lane >> 4;     // gather group 0..3
    int q = lane & 15;     // position in group; covers features 4q..4q+3
    float bl_r = bl[lane];
    float g_r  = gamma[lane];
    float be_r = beta[lane];

    for (int base = blockIdx.x * 4; base < n; base += gridDim.x * 4) {
        int r = base + wave;
        if (r >= n) continue;
        int rs = row_start[r];
        int re = row_start[r + 1];
        int deg = re - rs;

        float ax = 0.0f, ay = 0.0f, az = 0.0f, aw = 0.0f;
        for (int jb = 0; jb < deg; jb += 64) {
            int nb = deg - jb; if (nb > 64) nb = 64;
            int idxv = (jb + lane < deg) ? csr_src[rs + jb + lane] : 0;
            int c = 0;
            for (; c + 16 <= nb; c += 16) {
                int s0 = __shfl(idxv, c + g);
                int s1 = __shfl(idxv, c + 4 + g);
                int s2 = __shfl(idxv, c + 8 + g);
                int s3 = __shfl(idxv, c + 12 + g);
                float4 v0 = *reinterpret_cast<const float4*>(hp + (size_t)s0 * DIM + q * 4);
                float4 v1 = *reinterpret_cast<const float4*>(hp + (size_t)s1 * DIM + q * 4);
                float4 v2 = *reinterpret_cast<const float4*>(hp + (size_t)s2 * DIM + q * 4);
                float4 v3 = *reinterpret_cast<const float4*>(hp + (size_t)s3 * DIM + q * 4);
                ax += v0.x + v1.x + v2.x + v3.x;
                ay += v0.y + v1.y + v2.y + v3.y;
                az += v0.z + v1.z + v2.z + v3.z;
                aw += v0.w + v1.w + v2.w + v3.w;
            }
            for (; c + 4 <= nb; c += 4) {
                int s = __shfl(idxv, c + g);
                float4 v = *reinterpret_cast<const float4*>(hp + (size_t)s * DIM + q * 4);
                ax += v.x; ay += v.y; az += v.z; aw += v.w;
            }
            int rem = nb - c;
            if (rem > 0) {
                int s = __shfl(idxv, c + (g < rem ? g : 0));
                if (g < rem) {
                    float4 v = *reinterpret_cast<const float4*>(hp + (size_t)s * DIM + q * 4);
                    ax += v.x; ay += v.y; az += v.z; aw += v.w;
                }
            }
        }
        // merge the 4 group-partials (lanes q, q+16, q+32, q+48)
        ax += __shfl_xor(ax, 16); ax += __shfl_xor(ax, 32);
        ay += __shfl_xor(ay, 16); ay += __shfl_xor(ay, 32);
        az += __shfl_xor(az, 16); az += __shfl_xor(az, 32);
        aw += __shfl_xor(aw, 16); aw += __shfl_xor(aw, 32);

        float inv_dg = 1.0f / (float)(deg > 1 ? deg : 1);
        float avx = ax * inv_dg, avy = ay * inv_dg, avz = az * inv_dg, avw = aw * inv_dg;
        float hval = h[(size_t)r * DIM + lane];

        float o = bl_r;
        #pragma unroll
        for (int kk = 0; kk < 16; ++kk) {
            // features f = 4*kk + j ; av component j lives in lane kk (all groups equal)
            float b0 = __shfl(avx, kk);
            float b1 = __shfl(avy, kk);
            float b2 = __shfl(avz, kk);
            float b3 = __shfl(avw, kk);
            float h0 = __shfl(hval, 4 * kk + 0);
            float h1 = __shfl(hval, 4 * kk + 1);
            float h2 = __shfl(hval, 4 * kk + 2);
            float h3 = __shfl(hval, 4 * kk + 3);
            int f0 = 4 * kk + 0, f1 = 4 * kk + 1, f2 = 4 * kk + 2, f3 = 4 * kk + 3;
            o += b0 * WlT[(f0 << 6) | (lane ^ f0)] + h0 * WrT[(f0 << 6) | (lane ^ f0)];
            o += b1 * WlT[(f1 << 6) | (lane ^ f1)] + h1 * WrT[(f1 << 6) | (lane ^ f1)];
            o += b2 * WlT[(f2 << 6) | (lane ^ f2)] + h2 * WrT[(f2 << 6) | (lane ^ f2)];
            o += b3 * WlT[(f3 << 6) | (lane ^ f3)] + h3 * WrT[(f3 << 6) | (lane ^ f3)];
        }
        // LayerNorm across 64 lanes (biased variance, eps=1e-5)
        float mu = o;
        #pragma unroll
        for (int off = 32; off > 0; off >>= 1) mu += __shfl_xor(mu, off);
        mu *= (1.0f / 64.0f);
        float d0 = o - mu;
        float var = d0 * d0;
        #pragma unroll
        for (int off = 32; off > 0; off >>= 1) var += __shfl_xor(var, off);
        var *= (1.0f / 64.0f);
        float inv = rsqrtf(var + 1e-5f);
        out[(size_t)r * DIM + lane] = d0 * inv * g_r + be_r;
    }
}

extern "C" void kernel_launch(void* const* d_in, const int* in_sizes, int n_in,
                              void* d_out, int out_size, void* d_ws, size_t ws_size,
                              hipStream_t stream)
{
    const float* x      = (const float*)d_in[0];
    const int*   ei     = (const int*)d_in[1];
    const float* W_proj = (const float*)d_in[2];
    const float* b_proj = (const float*)d_in[3];
    const float* W_l    = (const float*)d_in[4];
    const float* b_l    = (const float*)d_in[5];
    const float* W_r    = (const float*)d_in[6];
    const float* gamma  = (const float*)d_in[7];
    const float* beta   = (const float*)d_in[8];

    const int N = in_sizes[0] / DIM;
    const int E = in_sizes[1] / 2;
    const int L = in_sizes[2] / (DIM * DIM);

    const int* src  = ei;
    const int* dstp = ei + E;

    const int nblocks = (N + 255) / 256;

    float* hp        = (float*)d_ws;
    float* h1        = hp + (size_t)N * DIM;
    int*   degi      = (int*)(h1 + (size_t)N * DIM);
    int*   row_start = degi + N;
    int*   cursor    = row_start + N + 1;
    int*   csr_src   = cursor + N;
    int*   blockSums = csr_src + E;

    // ---- build CSR (once; shared by both layers) ----
    hipMemsetAsync(degi, 0, (size_t)N * sizeof(int), stream);
    hist_kernel<<<2048, 256, 0, stream>>>(dstp, degi, E);
    scanA_kernel<<<nblocks, 256, 0, stream>>>(degi, blockSums, N);
    scanB_kernel<<<1, 256, 0, stream>>>(blockSums, nblocks);
    scanC_kernel<<<nblocks, 256, 0, stream>>>(degi, blockSums, row_start, cursor, N);
    bucket_kernel<<<2048, 256, 0, stream>>>(src, dstp, cursor, csr_src, E);

    // ---- layers ----
    const float* hin = x;
    for (int l = 0; l < L; ++l) {
        proj_kernel<<<2048, 256, 0, stream>>>(hin, W_proj + (size_t)l * DIM * DIM,
                                              b_proj + (size_t)l * DIM, hp, N);
        float* outp = (l == L - 1) ? (float*)d_out : h1;
        agg_combine_ln_kernel<<<2048, 256, 0, stream>>>(hin, hp, row_start, csr_src,
                                                        W_l + (size_t)l * DIM * DIM, b_l + (size_t)l * DIM,
                                                        W_r + (size_t)l * DIM * DIM,
                                                        gamma + (size_t)l * DIM, beta + (size_t)l * DIM,
                                                        outp, N);
        hin = h1;
    }
}

// Round 5
// 221.571 us; speedup vs baseline: 2.0505x; 1.9865x over previous
//
#include <hip/hip_runtime.h>

#define DIM 64

typedef __attribute__((ext_vector_type(8))) short bf16x8;
typedef __attribute__((ext_vector_type(4))) float f32x4;

__device__ inline unsigned short f2bf(float f) {
    unsigned int u = __float_as_uint(f);
    u = (u + 0x7fffu + ((u >> 16) & 1u)) >> 16;   // RTNE
    return (unsigned short)u;
}
__device__ inline float bf2f(unsigned int lo16) {
    return __uint_as_float(lo16 << 16);
}

// ---------------- int degree histogram ----------------
__global__ void hist_kernel(const int* __restrict__ dst, int* __restrict__ deg, int E) {
    int tid = blockIdx.x * blockDim.x + threadIdx.x;
    int stride = gridDim.x * blockDim.x;
    for (int e = tid; e < E; e += stride)
        atomicAdd(&deg[dst[e]], 1);
}

// ---------------- scan stage A: per-block sums ----------------
__global__ void scanA_kernel(const int* __restrict__ deg, int* __restrict__ blockSums, int N) {
    __shared__ int tmp[256];
    int t = threadIdx.x;
    int i = blockIdx.x * 256 + t;
    int v = (i < N) ? deg[i] : 0;
    tmp[t] = v;
    __syncthreads();
    for (int off = 128; off > 0; off >>= 1) {
        if (t < off) tmp[t] += tmp[t + off];
        __syncthreads();
    }
    if (t == 0) blockSums[blockIdx.x] = tmp[0];
}

// ---------------- scan stage B: exclusive scan of block sums (1 block) ----------------
__global__ void scanB_kernel(int* __restrict__ blockSums, int nblocks) {
    __shared__ int tmp[256];
    __shared__ int carry;
    int t = threadIdx.x;
    if (t == 0) carry = 0;
    __syncthreads();
    for (int base = 0; base < nblocks; base += 256) {
        int idx = base + t;
        int v = (idx < nblocks) ? blockSums[idx] : 0;
        tmp[t] = v;
        __syncthreads();
        for (int off = 1; off < 256; off <<= 1) {
            int add = (t >= off) ? tmp[t - off] : 0;
            __syncthreads();
            tmp[t] += add;
            __syncthreads();
        }
        int incl = tmp[t];
        int excl = incl - v + carry;
        if (idx < nblocks) blockSums[idx] = excl;
        int chunkTotal = tmp[255];
        __syncthreads();
        if (t == 0) carry += chunkTotal;
        __syncthreads();
    }
}

// ---------------- scan stage C: per-element exclusive offsets ----------------
__global__ void scanC_kernel(const int* __restrict__ deg, const int* __restrict__ blockOff,
                             int* __restrict__ row_start, int* __restrict__ cursor, int N) {
    __shared__ int tmp[256];
    int b = blockIdx.x, t = threadIdx.x;
    int i = b * 256 + t;
    int v = (i < N) ? deg[i] : 0;
    tmp[t] = v;
    __syncthreads();
    for (int off = 1; off < 256; off <<= 1) {
        int add = (t >= off) ? tmp[t - off] : 0;
        __syncthreads();
        tmp[t] += add;
        __syncthreads();
    }
    int excl = tmp[t] - v + blockOff[b];
    if (i < N) {
        row_start[i] = excl;
        cursor[i] = excl;
        if (i == N - 1) row_start[N] = excl + v;
    }
}

// ---------------- bucket fill: csr_src grouped by dst ----------------
__global__ void bucket_kernel(const int* __restrict__ src, const int* __restrict__ dst,
                              int* __restrict__ cursor, int* __restrict__ csr_src, int E) {
    int tid = blockIdx.x * blockDim.x + threadIdx.x;
    int stride = gridDim.x * blockDim.x;
    for (int e = tid; e < E; e += stride) {
        int p = atomicAdd(&cursor[dst[e]], 1);
        csr_src[p] = src[e];
    }
}

// ---------------- fp32 -> bf16 convert (x once per call) ----------------
__global__ void cvt_kernel(const float* __restrict__ x, unsigned short* __restrict__ x16, int total8) {
    int t = blockIdx.x * blockDim.x + threadIdx.x;
    int stride = gridDim.x * blockDim.x;
    for (int i = t; i < total8; i += stride) {
        const float4* p = reinterpret_cast<const float4*>(x + (size_t)i * 8);
        float4 u = p[0], w = p[1];
        uint4 o;
        o.x = f2bf(u.x) | ((unsigned int)f2bf(u.y) << 16);
        o.y = f2bf(u.z) | ((unsigned int)f2bf(u.w) << 16);
        o.z = f2bf(w.x) | ((unsigned int)f2bf(w.y) << 16);
        o.w = f2bf(w.z) | ((unsigned int)f2bf(w.w) << 16);
        *reinterpret_cast<uint4*>(x16 + (size_t)i * 8) = o;
    }
}

// load 8 consecutive fp32 weights W[n*64 + k0 .. k0+7] as a bf16x8 fragment
__device__ inline bf16x8 load_wfrag(const float* __restrict__ W, int n, int k0) {
    const float4* p = reinterpret_cast<const float4*>(W + (size_t)n * DIM + k0);
    float4 w0 = p[0], w1 = p[1];
    bf16x8 b;
    b[0] = (short)f2bf(w0.x); b[1] = (short)f2bf(w0.y);
    b[2] = (short)f2bf(w0.z); b[3] = (short)f2bf(w0.w);
    b[4] = (short)f2bf(w1.x); b[5] = (short)f2bf(w1.y);
    b[6] = (short)f2bf(w1.z); b[7] = (short)f2bf(w1.w);
    return b;
}

// ---------------- proj: hp16 = relu(A16 @ Wp^T + bp), MFMA 16x16x32 bf16 ----------------
// wave handles 16 rows x 64 cols. A: lane row = lane&15, k = (lane>>4)*8+j (+32*kstep).
// B[k][n] = Wp[n][k]; lane col = lane&15, same k mapping (k-permutation cancels).
__global__ void __launch_bounds__(256, 4)
proj_gemm_kernel(const unsigned short* __restrict__ A16,
                 const float* __restrict__ Wp, const float* __restrict__ bp,
                 unsigned short* __restrict__ hp16, int M)
{
    int lane = threadIdx.x & 63, wave = threadIdx.x >> 6;
    int lo = lane & 15, hi = lane >> 4;
    int rowbase = (blockIdx.x * 4 + wave) * 16;
    if (rowbase >= M) return;     // M % 16 == 0, so valid waves are fully in-bounds

    bf16x8 B[2][4];
    #pragma unroll
    for (int ks = 0; ks < 2; ++ks)
        #pragma unroll
        for (int nt = 0; nt < 4; ++nt)
            B[ks][nt] = load_wfrag(Wp, nt * 16 + lo, ks * 32 + hi * 8);

    f32x4 z = {0.f, 0.f, 0.f, 0.f};
    f32x4 acc[4] = {z, z, z, z};
    #pragma unroll
    for (int ks = 0; ks < 2; ++ks) {
        bf16x8 a = *reinterpret_cast<const bf16x8*>(A16 + (size_t)(rowbase + lo) * DIM + ks * 32 + hi * 8);
        #pragma unroll
        for (int nt = 0; nt < 4; ++nt)
            acc[nt] = __builtin_amdgcn_mfma_f32_16x16x32_bf16(a, B[ks][nt], acc[nt], 0, 0, 0);
    }
    #pragma unroll
    for (int nt = 0; nt < 4; ++nt) {
        int col = nt * 16 + lo;
        float b = bp[col];
        #pragma unroll
        for (int i = 0; i < 4; ++i) {
            int row = rowbase + hi * 4 + i;
            float v = fmaxf(acc[nt][i] + b, 0.0f);
            hp16[(size_t)row * DIM + col] = f2bf(v);
        }
    }
}

// ---------------- gather: agg16[r] = mean of hp16 rows of incoming neighbors ----------------
// 8 groups x 8 lanes; group g loads whole 128B bf16 rows (8 lanes x 16B); fp32 accum.
__global__ void __launch_bounds__(256, 6)
gather_mean_kernel(const unsigned short* __restrict__ hp16,
                   const int* __restrict__ row_start, const int* __restrict__ csr_src,
                   unsigned short* __restrict__ agg16, int n)
{
    int wave = threadIdx.x >> 6, lane = threadIdx.x & 63;
    int r = blockIdx.x * 4 + wave;
    if (r >= n) return;
    int rs = row_start[r], re = row_start[r + 1];
    int deg = re - rs;
    int g = lane >> 3, q = lane & 7;

    float a0 = 0.f, a1 = 0.f, a2 = 0.f, a3 = 0.f, a4 = 0.f, a5 = 0.f, a6 = 0.f, a7 = 0.f;

    #define ACCUM8(v)                                   \
        a0 += bf2f((v).x & 0xffffu); a1 += bf2f((v).x >> 16); \
        a2 += bf2f((v).y & 0xffffu); a3 += bf2f((v).y >> 16); \
        a4 += bf2f((v).z & 0xffffu); a5 += bf2f((v).z >> 16); \
        a6 += bf2f((v).w & 0xffffu); a7 += bf2f((v).w >> 16);

    for (int jb = 0; jb < deg; jb += 64) {
        int nb = deg - jb; if (nb > 64) nb = 64;
        int idxv = (jb + lane < deg) ? csr_src[rs + jb + lane] : 0;
        int c = 0;
        for (; c + 32 <= nb; c += 32) {
            int s0 = __shfl(idxv, c + g);
            int s1 = __shfl(idxv, c + 8 + g);
            int s2 = __shfl(idxv, c + 16 + g);
            int s3 = __shfl(idxv, c + 24 + g);
            uint4 v0 = *reinterpret_cast<const uint4*>(hp16 + (size_t)s0 * DIM + q * 8);
            uint4 v1 = *reinterpret_cast<const uint4*>(hp16 + (size_t)s1 * DIM + q * 8);
            uint4 v2 = *reinterpret_cast<const uint4*>(hp16 + (size_t)s2 * DIM + q * 8);
            uint4 v3 = *reinterpret_cast<const uint4*>(hp16 + (size_t)s3 * DIM + q * 8);
            ACCUM8(v0) ACCUM8(v1) ACCUM8(v2) ACCUM8(v3)
        }
        for (; c + 8 <= nb; c += 8) {
            int s = __shfl(idxv, c + g);
            uint4 v = *reinterpret_cast<const uint4*>(hp16 + (size_t)s * DIM + q * 8);
            ACCUM8(v)
        }
        int rem = nb - c;
        if (rem > 0) {
            int li = c + g; if (li >= nb) li = c;
            int s = __shfl(idxv, li);
            if (g < rem) {
                uint4 v = *reinterpret_cast<const uint4*>(hp16 + (size_t)s * DIM + q * 8);
                ACCUM8(v)
            }
        }
    }
    #undef ACCUM8

    // merge the 8 group-partials (xor over g bits: 8,16,32)
    #define MRG(x) x += __shfl_xor(x, 8); x += __shfl_xor(x, 16); x += __shfl_xor(x, 32);
    MRG(a0) MRG(a1) MRG(a2) MRG(a3) MRG(a4) MRG(a5) MRG(a6) MRG(a7)
    #undef MRG

    if (lane < 8) {   // g==0, q==lane
        float invd = 1.0f / (float)(deg > 1 ? deg : 1);
        uint4 o;
        o.x = f2bf(a0 * invd) | ((unsigned int)f2bf(a1 * invd) << 16);
        o.y = f2bf(a2 * invd) | ((unsigned int)f2bf(a3 * invd) << 16);
        o.z = f2bf(a4 * invd) | ((unsigned int)f2bf(a5 * invd) << 16);
        o.w = f2bf(a6 * invd) | ((unsigned int)f2bf(a7 * invd) << 16);
        *reinterpret_cast<uint4*>(agg16 + (size_t)r * DIM + lane * 8) = o;
    }
}

// ---------------- combine: out = LN(agg@Wl^T + bl + h@Wr^T) * gamma + beta ----------------
// K=128: ksteps 0,1 = (agg16, Wl); ksteps 2,3 = (h16, Wr). LN fused in epilogue.
template<bool FINAL>
__global__ void __launch_bounds__(256, 4)
combine_gemm_ln_kernel(const unsigned short* __restrict__ Ag16,
                       const unsigned short* __restrict__ H16,
                       const float* __restrict__ Wl, const float* __restrict__ bl,
                       const float* __restrict__ Wr,
                       const float* __restrict__ gamma, const float* __restrict__ beta,
                       void* __restrict__ outv, int M)
{
    int lane = threadIdx.x & 63, wave = threadIdx.x >> 6;
    int lo = lane & 15, hi = lane >> 4;
    int rowbase = (blockIdx.x * 4 + wave) * 16;
    if (rowbase >= M) return;

    bf16x8 B[4][4];
    #pragma unroll
    for (int ks = 0; ks < 2; ++ks)
        #pragma unroll
        for (int nt = 0; nt < 4; ++nt)
            B[ks][nt] = load_wfrag(Wl, nt * 16 + lo, ks * 32 + hi * 8);
    #pragma unroll
    for (int ks = 2; ks < 4; ++ks)
        #pragma unroll
        for (int nt = 0; nt < 4; ++nt)
            B[ks][nt] = load_wfrag(Wr, nt * 16 + lo, (ks - 2) * 32 + hi * 8);

    f32x4 z = {0.f, 0.f, 0.f, 0.f};
    f32x4 acc[4] = {z, z, z, z};
    #pragma unroll
    for (int ks = 0; ks < 2; ++ks) {
        bf16x8 a = *reinterpret_cast<const bf16x8*>(Ag16 + (size_t)(rowbase + lo) * DIM + ks * 32 + hi * 8);
        #pragma unroll
        for (int nt = 0; nt < 4; ++nt)
            acc[nt] = __builtin_amdgcn_mfma_f32_16x16x32_bf16(a, B[ks][nt], acc[nt], 0, 0, 0);
    }
    #pragma unroll
    for (int ks = 2; ks < 4; ++ks) {
        bf16x8 a = *reinterpret_cast<const bf16x8*>(H16 + (size_t)(rowbase + lo) * DIM + (ks - 2) * 32 + hi * 8);
        #pragma unroll
        for (int nt = 0; nt < 4; ++nt)
            acc[nt] = __builtin_amdgcn_mfma_f32_16x16x32_bf16(a, B[ks][nt], acc[nt], 0, 0, 0);
    }

    // epilogue: bias + LayerNorm over 64 cols (rows live across the 16 lanes of each hi-group)
    float vals[4][4];
    float sum0 = 0.f, sum1 = 0.f, sum2 = 0.f, sum3 = 0.f;
    float sq0 = 0.f, sq1 = 0.f, sq2 = 0.f, sq3 = 0.f;
    #pragma unroll
    for (int nt = 0; nt < 4; ++nt) {
        float b = bl[nt * 16 + lo];
        float v0 = acc[nt][0] + b, v1 = acc[nt][1] + b, v2 = acc[nt][2] + b, v3 = acc[nt][3] + b;
        vals[nt][0] = v0; vals[nt][1] = v1; vals[nt][2] = v2; vals[nt][3] = v3;
        sum0 += v0; sum1 += v1; sum2 += v2; sum3 += v3;
        sq0 += v0 * v0; sq1 += v1 * v1; sq2 += v2 * v2; sq3 += v3 * v3;
    }
    #pragma unroll
    for (int off = 1; off < 16; off <<= 1) {
        sum0 += __shfl_xor(sum0, off); sq0 += __shfl_xor(sq0, off);
        sum1 += __shfl_xor(sum1, off); sq1 += __shfl_xor(sq1, off);
        sum2 += __shfl_xor(sum2, off); sq2 += __shfl_xor(sq2, off);
        sum3 += __shfl_xor(sum3, off); sq3 += __shfl_xor(sq3, off);
    }
    float mu0 = sum0 * (1.0f / 64.0f), mu1 = sum1 * (1.0f / 64.0f);
    float mu2 = sum2 * (1.0f / 64.0f), mu3 = sum3 * (1.0f / 64.0f);
    float iv0 = rsqrtf(sq0 * (1.0f / 64.0f) - mu0 * mu0 + 1e-5f);
    float iv1 = rsqrtf(sq1 * (1.0f / 64.0f) - mu1 * mu1 + 1e-5f);
    float iv2 = rsqrtf(sq2 * (1.0f / 64.0f) - mu2 * mu2 + 1e-5f);
    float iv3 = rsqrtf(sq3 * (1.0f / 64.0f) - mu3 * mu3 + 1e-5f);

    #pragma unroll
    for (int nt = 0; nt < 4; ++nt) {
        int col = nt * 16 + lo;
        float gm = gamma[col], be = beta[col];
        float o0 = (vals[nt][0] - mu0) * iv0 * gm + be;
        float o1 = (vals[nt][1] - mu1) * iv1 * gm + be;
        float o2 = (vals[nt][2] - mu2) * iv2 * gm + be;
        float o3 = (vals[nt][3] - mu3) * iv3 * gm + be;
        size_t r0 = (size_t)(rowbase + hi * 4) * DIM + col;
        if (FINAL) {
            float* out = (float*)outv;
            out[r0] = o0; out[r0 + DIM] = o1; out[r0 + 2 * DIM] = o2; out[r0 + 3 * DIM] = o3;
        } else {
            unsigned short* out = (unsigned short*)outv;
            out[r0] = f2bf(o0); out[r0 + DIM] = f2bf(o1);
            out[r0 + 2 * DIM] = f2bf(o2); out[r0 + 3 * DIM] = f2bf(o3);
        }
    }
}

extern "C" void kernel_launch(void* const* d_in, const int* in_sizes, int n_in,
                              void* d_out, int out_size, void* d_ws, size_t ws_size,
                              hipStream_t stream)
{
    const float* x      = (const float*)d_in[0];
    const int*   ei     = (const int*)d_in[1];
    const float* W_proj = (const float*)d_in[2];
    const float* b_proj = (const float*)d_in[3];
    const float* W_l    = (const float*)d_in[4];
    const float* b_l    = (const float*)d_in[5];
    const float* W_r    = (const float*)d_in[6];
    const float* gamma  = (const float*)d_in[7];
    const float* beta   = (const float*)d_in[8];

    const int N = in_sizes[0] / DIM;
    const int E = in_sizes[1] / 2;
    const int L = in_sizes[2] / (DIM * DIM);

    const int* src  = ei;
    const int* dstp = ei + E;

    const int nblocks = (N + 255) / 256;

    // ws layout (bf16 feature buffers first, 16B aligned)
    unsigned short* x16   = (unsigned short*)d_ws;
    unsigned short* h16   = x16  + (size_t)N * DIM;
    unsigned short* hp16  = h16  + (size_t)N * DIM;
    unsigned short* agg16 = hp16 + (size_t)N * DIM;
    int* degi      = (int*)(agg16 + (size_t)N * DIM);
    int* row_start = degi + N;
    int* cursor    = row_start + N + 1;
    int* csr_src   = cursor + N;
    int* blockSums = csr_src + E;

    // ---- build CSR (once; shared by both layers) ----
    hipMemsetAsync(degi, 0, (size_t)N * sizeof(int), stream);
    hist_kernel<<<2048, 256, 0, stream>>>(dstp, degi, E);
    scanA_kernel<<<nblocks, 256, 0, stream>>>(degi, blockSums, N);
    scanB_kernel<<<1, 256, 0, stream>>>(blockSums, nblocks);
    scanC_kernel<<<nblocks, 256, 0, stream>>>(degi, blockSums, row_start, cursor, N);
    bucket_kernel<<<2048, 256, 0, stream>>>(src, dstp, cursor, csr_src, E);

    // ---- x -> bf16 once ----
    cvt_kernel<<<1563, 256, 0, stream>>>(x, x16, N * DIM / 8);

    const int gemmBlocks = (N + 63) / 64;
    const int gatherBlocks = (N + 3) / 4;

    // ---- layers ----
    const unsigned short* hin16 = x16;
    for (int l = 0; l < L; ++l) {
        proj_gemm_kernel<<<gemmBlocks, 256, 0, stream>>>(
            hin16, W_proj + (size_t)l * DIM * DIM, b_proj + (size_t)l * DIM, hp16, N);
        gather_mean_kernel<<<gatherBlocks, 256, 0, stream>>>(hp16, row_start, csr_src, agg16, N);
        if (l == L - 1) {
            combine_gemm_ln_kernel<true><<<gemmBlocks, 256, 0, stream>>>(
                agg16, hin16, W_l + (size_t)l * DIM * DIM, b_l + (size_t)l * DIM,
                W_r + (size_t)l * DIM * DIM, gamma + (size_t)l * DIM, beta + (size_t)l * DIM,
                d_out, N);
        } else {
            combine_gemm_ln_kernel<false><<<gemmBlocks, 256, 0, stream>>>(
                agg16, hin16, W_l + (size_t)l * DIM * DIM, b_l + (size_t)l * DIM,
                W_r + (size_t)l * DIM * DIM, gamma + (size_t)l * DIM, beta + (size_t)l * DIM,
                h16, N);
        }
        hin16 = h16;
    }
}